// Round 1
// baseline (296.986 us; speedup 1.0000x reference)
//
#include <hip/hip_runtime.h>
#include <hip/hip_bf16.h>
#include <stdint.h>

#define NN 4096
#define BATCH 1024
#define SEG 128
#define NSEG 32
#define DPAD 8192

typedef __bf16 bf16x8 __attribute__((ext_vector_type(8)));
typedef float f32x4 __attribute__((ext_vector_type(4)));

__device__ __forceinline__ unsigned short f2bf(float f) {
    uint32_t u = __builtin_bit_cast(uint32_t, f);
    uint32_t r = (u + 0x7FFFu + ((u >> 16) & 1u)) >> 16;
    return (unsigned short)r;
}

// ---- transpose G,H (R x N, R=4) into float4-per-position arrays ----
__global__ void k_prep(const float* __restrict__ G, const float* __restrict__ H,
                       float4* __restrict__ G4, float4* __restrict__ H4) {
    int p = blockIdx.x * 256 + threadIdx.x;
    if (p < NN) {
        G4[p] = make_float4(G[p], G[NN + p], G[2 * NN + p], G[3 * NN + p]);
        H4[p] = make_float4(H[p], H[NN + p], H[2 * NN + p], H[3 * NN + p]);
    }
}

// ---- convert x fp32 -> bf16 ----
__global__ void k_convert(const float4* __restrict__ x4, ushort4* __restrict__ xb4) {
    int t = blockIdx.x * 256 + threadIdx.x;  // BATCH*NN/4 threads exactly
    float4 a = x4[t];
    ushort4 o;
    o.x = f2bf(a.x); o.y = f2bf(a.y); o.z = f2bf(a.z); o.w = f2bf(a.w);
    xb4[t] = o;
}

// ---- pass 1: per-(diagonal, segment) affine map (A = prod c, B = local sum) ----
// M[i,k] = f(i,k) + sA_i*sB_k*M[i-1,k-1]; along diag (i-k = o), step t.
__global__ void k_pass1(const float4* __restrict__ G4, const float4* __restrict__ H4,
                        const float* __restrict__ sA, const float* __restrict__ sB,
                        float2* __restrict__ seg) {
    int tid = blockIdx.x * 256 + threadIdx.x;
    int s = tid >> 13;        // segment index 0..31
    int dd = tid & (DPAD - 1);
    int o = dd - (NN - 1);
    if (o > NN - 1) return;
    int ao = o < 0 ? -o : o;
    int L = NN - ao;
    int nseg = (L + SEG - 1) >> 7;
    if (s >= nseg) return;
    int t0 = s * SEG;
    int tend = t0 + SEG; if (tend > L) tend = L;
    float M = 0.f, Aacc = 1.f;
    for (int t = t0; t < tend; ++t) {
        int i = (o >= 0) ? (t + o) : t;
        int k = (o >= 0) ? t : (t - o);
        float4 g = G4[i], h = H4[k];
        float f = g.x * h.x + g.y * h.y + g.z * h.z + g.w * h.w;
        float c = (t == 0) ? 0.f : sA[i - 1] * sB[k - 1];
        M = fmaf(c, M, f);
        Aacc *= c;
    }
    seg[s * DPAD + dd] = make_float2(Aacc, M);
}

// ---- pass 2: scan affine maps along each diagonal -> carry-in per segment ----
__global__ void k_pass2(const float2* __restrict__ seg, float* __restrict__ carr) {
    int dd = blockIdx.x * 256 + threadIdx.x;
    if (dd >= DPAD) return;
    int o = dd - (NN - 1);
    if (o > NN - 1) return;
    int ao = o < 0 ? -o : o;
    int L = NN - ao;
    int nseg = (L + SEG - 1) >> 7;
    float Min = 0.f;
    for (int s = 0; s < nseg; ++s) {
        carr[s * DPAD + dd] = Min;
        float2 ab = seg[s * DPAD + dd];
        Min = fmaf(ab.x, Min, ab.y);
    }
}

// ---- pass 3: recompute recurrence with carry, write V[i][k] = M[i,k] in bf16 ----
__global__ void k_pass3(const float4* __restrict__ G4, const float4* __restrict__ H4,
                        const float* __restrict__ sA, const float* __restrict__ sB,
                        const float* __restrict__ carr, unsigned short* __restrict__ V) {
    int tid = blockIdx.x * 256 + threadIdx.x;
    int s = tid >> 13;
    int dd = tid & (DPAD - 1);
    int o = dd - (NN - 1);
    if (o > NN - 1) return;
    int ao = o < 0 ? -o : o;
    int L = NN - ao;
    int nseg = (L + SEG - 1) >> 7;
    if (s >= nseg) return;
    int t0 = s * SEG;
    int tend = t0 + SEG; if (tend > L) tend = L;
    float M = carr[s * DPAD + dd];
    for (int t = t0; t < tend; ++t) {
        int i = (o >= 0) ? (t + o) : t;
        int k = (o >= 0) ? t : (t - o);
        float4 g = G4[i], h = H4[k];
        float f = g.x * h.x + g.y * h.y + g.z * h.z + g.w * h.w;
        float c = (t == 0) ? 0.f : sA[i - 1] * sB[k - 1];
        M = fmaf(c, M, f);
        V[(size_t)i * NN + k] = f2bf(M);
    }
}

// ---- GEMM: out[b,i] = sum_k xb[b,k] * V[i][k] + bias[i]  (B^T-layout GEMM) ----
// 128x128 tile, BK=64, 4 waves (2x2), each wave 64x64 = 4x4 frags of 16x16x32 bf16 MFMA.
__global__ __launch_bounds__(256) void k_gemm(const unsigned short* __restrict__ A,
                                              const unsigned short* __restrict__ Bv,
                                              const float* __restrict__ bias,
                                              float* __restrict__ C) {
    __shared__ unsigned short lA[128 * 64];  // [row m][k] row-major, 128B rows
    __shared__ unsigned short lB[128 * 64];  // [row n(i)][k] row-major

    int bm = blockIdx.x;  // 0..7   (batch rows / 128)
    int bn = blockIdx.y;  // 0..31  (output cols / 128)
    int tid = threadIdx.x;
    int lane = tid & 63;
    int wid = tid >> 6;
    int wm = wid >> 1, wn = wid & 1;

    // staging pointers: chunk ca = wid*4+c covers LDS bytes [ca*1024, ca*1024+1024)
    // LDS linear byte off = ca*1024 + lane*16 -> row = ca*8 + (lane>>3), colb = (lane&7)*16
    const unsigned short* aptr[4];
    const unsigned short* bptr[4];
#pragma unroll
    for (int c = 0; c < 4; ++c) {
        int ca = wid * 4 + c;
        int row = ca * 8 + (lane >> 3);
        int cole = (lane & 7) * 8;  // element offset within row (8 bf16 = 16B)
        aptr[c] = A + ((size_t)(bm * 128 + row) * NN) + cole;
        bptr[c] = Bv + ((size_t)(bn * 128 + row) * NN) + cole;
    }

    f32x4 acc[4][4];
#pragma unroll
    for (int i = 0; i < 4; ++i)
#pragma unroll
        for (int j = 0; j < 4; ++j) acc[i][j] = (f32x4){0.f, 0.f, 0.f, 0.f};

    for (int kt = 0; kt < NN / 64; ++kt) {
#pragma unroll
        for (int c = 0; c < 4; ++c) {
            int ca = wid * 4 + c;
            __builtin_amdgcn_global_load_lds(
                (const __attribute__((address_space(1))) uint32_t*)(aptr[c]),
                (__attribute__((address_space(3))) uint32_t*)(&lA[ca * 512]), 16, 0, 0);
            __builtin_amdgcn_global_load_lds(
                (const __attribute__((address_space(1))) uint32_t*)(bptr[c]),
                (__attribute__((address_space(3))) uint32_t*)(&lB[ca * 512]), 16, 0, 0);
            aptr[c] += 64;
            bptr[c] += 64;
        }
        __syncthreads();  // drains vmcnt before barrier -> LDS ready
#pragma unroll
        for (int kk = 0; kk < 2; ++kk) {
            bf16x8 af[4], bf[4];
#pragma unroll
            for (int mf = 0; mf < 4; ++mf)
                af[mf] = *(const bf16x8*)&lA[(wm * 64 + mf * 16 + (lane & 15)) * 64 + kk * 32 + (lane >> 4) * 8];
#pragma unroll
            for (int nf = 0; nf < 4; ++nf)
                bf[nf] = *(const bf16x8*)&lB[(wn * 64 + nf * 16 + (lane & 15)) * 64 + kk * 32 + (lane >> 4) * 8];
#pragma unroll
            for (int mf = 0; mf < 4; ++mf)
#pragma unroll
                for (int nf = 0; nf < 4; ++nf)
                    acc[mf][nf] = __builtin_amdgcn_mfma_f32_16x16x32_bf16(af[mf], bf[nf], acc[mf][nf], 0, 0, 0);
        }
        __syncthreads();
    }

    // epilogue: D frag layout col = lane&15, row = (lane>>4)*4 + r
#pragma unroll
    for (int nf = 0; nf < 4; ++nf) {
        int col = bn * 128 + wn * 64 + nf * 16 + (lane & 15);
        float bv = bias[col];
#pragma unroll
        for (int mf = 0; mf < 4; ++mf) {
            f32x4 v = acc[mf][nf];
            int row0 = bm * 128 + wm * 64 + mf * 16 + (lane >> 4) * 4;
#pragma unroll
            for (int r = 0; r < 4; ++r)
                C[(size_t)(row0 + r) * NN + col] = v[r] + bv;
        }
    }
}

extern "C" void kernel_launch(void* const* d_in, const int* in_sizes, int n_in,
                              void* d_out, int out_size, void* d_ws, size_t ws_size,
                              hipStream_t stream) {
    (void)in_sizes; (void)n_in; (void)out_size; (void)ws_size;
    const float* x  = (const float*)d_in[0];
    const float* sA = (const float*)d_in[1];
    const float* sB = (const float*)d_in[2];
    const float* G  = (const float*)d_in[3];
    const float* H  = (const float*)d_in[4];
    const float* bias = (const float*)d_in[5];
    float* out = (float*)d_out;

    char* ws = (char*)d_ws;
    unsigned short* V  = (unsigned short*)ws;            // 33,554,432 B
    unsigned short* xb = (unsigned short*)(ws + 33554432);  // 8,388,608 B
    float4* G4 = (float4*)(ws + 41943040);               // 65,536 B
    float4* H4 = (float4*)(ws + 42008576);               // 65,536 B
    float2* seg = (float2*)(ws + 42074112);              // 2,097,152 B
    float* carr = (float*)(ws + 44171264);               // 1,048,576 B
    // total ws need: 45,219,840 B

    hipLaunchKernelGGL(k_prep, dim3(16), dim3(256), 0, stream, G, H, G4, H4);
    hipLaunchKernelGGL(k_convert, dim3((BATCH * NN / 4) / 256), dim3(256), 0, stream,
                       (const float4*)x, (ushort4*)xb);
    hipLaunchKernelGGL(k_pass1, dim3((NSEG * DPAD) / 256), dim3(256), 0, stream,
                       G4, H4, sA, sB, seg);
    hipLaunchKernelGGL(k_pass2, dim3(DPAD / 256), dim3(256), 0, stream, seg, carr);
    hipLaunchKernelGGL(k_pass3, dim3((NSEG * DPAD) / 256), dim3(256), 0, stream,
                       G4, H4, sA, sB, carr, V);
    hipLaunchKernelGGL(k_gemm, dim3(BATCH / 128, NN / 128), dim3(256), 0, stream,
                       xb, V, bias, out);
}

// Round 2
// 259.855 us; speedup vs baseline: 1.1429x; 1.1429x over previous
//
#include <hip/hip_runtime.h>
#include <hip/hip_bf16.h>
#include <stdint.h>

#define NN 4096
#define BATCH 1024
#define SEG 128
#define NSEG 32
#define DPAD 8192
#define DGRP 256   // diagonals per pass3 block
#define TSEG 128   // steps per pass3 block (== SEG, matches carr granularity)

typedef __bf16 bf16x8 __attribute__((ext_vector_type(8)));
typedef float f32x4 __attribute__((ext_vector_type(4)));

__device__ __forceinline__ unsigned short f2bf(float f) {
    uint32_t u = __builtin_bit_cast(uint32_t, f);
    uint32_t r = (u + 0x7FFFu + ((u >> 16) & 1u)) >> 16;
    return (unsigned short)r;
}

// ---- transpose G,H (R x N, R=4) into float4-per-position arrays ----
__global__ void k_prep(const float* __restrict__ G, const float* __restrict__ H,
                       float4* __restrict__ G4, float4* __restrict__ H4) {
    int p = blockIdx.x * 256 + threadIdx.x;
    if (p < NN) {
        G4[p] = make_float4(G[p], G[NN + p], G[2 * NN + p], G[3 * NN + p]);
        H4[p] = make_float4(H[p], H[NN + p], H[2 * NN + p], H[3 * NN + p]);
    }
}

// ---- convert x fp32 -> bf16 ----
__global__ void k_convert(const float4* __restrict__ x4, ushort4* __restrict__ xb4) {
    int t = blockIdx.x * 256 + threadIdx.x;  // BATCH*NN/4 threads exactly
    float4 a = x4[t];
    ushort4 o;
    o.x = f2bf(a.x); o.y = f2bf(a.y); o.z = f2bf(a.z); o.w = f2bf(a.w);
    xb4[t] = o;
}

// ---- pass 1: per-(diagonal, segment) affine map (A = prod c, B = local sum) ----
// M[i,k] = f(i,k) + sA_i*sB_k*M[i-1,k-1]; along diag (i-k = o), step t.
__global__ void k_pass1(const float4* __restrict__ G4, const float4* __restrict__ H4,
                        const float* __restrict__ sA, const float* __restrict__ sB,
                        float2* __restrict__ seg) {
    int tid = blockIdx.x * 256 + threadIdx.x;
    int s = tid >> 13;        // segment index 0..31
    int dd = tid & (DPAD - 1);
    int o = dd - (NN - 1);
    if (o > NN - 1) return;
    int ao = o < 0 ? -o : o;
    int L = NN - ao;
    int nseg = (L + SEG - 1) >> 7;
    if (s >= nseg) return;
    int t0 = s * SEG;
    int tend = t0 + SEG; if (tend > L) tend = L;
    float M = 0.f, Aacc = 1.f;
    for (int t = t0; t < tend; ++t) {
        int i = (o >= 0) ? (t + o) : t;
        int k = (o >= 0) ? t : (t - o);
        float4 g = G4[i], h = H4[k];
        float f = g.x * h.x + g.y * h.y + g.z * h.z + g.w * h.w;
        float c = (t == 0) ? 0.f : sA[i - 1] * sB[k - 1];
        M = fmaf(c, M, f);
        Aacc *= c;
    }
    seg[s * DPAD + dd] = make_float2(Aacc, M);
}

// ---- pass 2: scan affine maps along each diagonal -> carry-in per segment ----
__global__ void k_pass2(const float2* __restrict__ seg, float* __restrict__ carr) {
    int dd = blockIdx.x * 256 + threadIdx.x;
    if (dd >= DPAD) return;
    int o = dd - (NN - 1);
    if (o > NN - 1) return;
    int ao = o < 0 ? -o : o;
    int L = NN - ao;
    int nseg = (L + SEG - 1) >> 7;
    float Min = 0.f;
    for (int s = 0; s < nseg; ++s) {
        carr[s * DPAD + dd] = Min;
        float2 ab = seg[s * DPAD + dd];
        Min = fmaf(ab.x, Min, ab.y);
    }
}

// ---- pass 3 (tiled): recompute recurrence with carry into LDS, coalesced V write ----
// Block = 256 diagonals x 128 steps parallelogram. Each output row i intersects
// the parallelogram in a contiguous k-run (<=256 elems) -> coalesced stores.
__global__ __launch_bounds__(256) void k_pass3t(
        const float4* __restrict__ G4, const float4* __restrict__ H4,
        const float* __restrict__ sA, const float* __restrict__ sB,
        const float* __restrict__ carr, unsigned short* __restrict__ V) {
    __shared__ unsigned short vals[TSEG][DGRP];  // [t_local][dd_local] = 64 KB

    int dg = blockIdx.x;        // 0..31 diagonal group
    int sg = blockIdx.y;        // 0..31 step segment
    int dd0 = dg * DGRP;
    int t0 = sg * TSEG;
    int o0 = dd0 - (NN - 1);
    int o_hi = o0 + DGRP - 1;

    // early-exit fully-empty blocks: longest diagonal in group
    int minabs = (o0 >= 0) ? o0 : ((o_hi < 0) ? -o_hi : 0);
    if (t0 >= NN - minabs) return;

    int tid = threadIdx.x;
    int dd = dd0 + tid;
    int o = dd - (NN - 1);
    int i0 = t0 + (o > 0 ? o : 0);
    int k0 = t0 - (o < 0 ? o : 0);

    float M = carr[sg * DPAD + dd];
#pragma unroll 4
    for (int tl = 0; tl < TSEG; ++tl) {
        int i = i0 + tl, k = k0 + tl;
        int ic = i < NN ? i : NN - 1;       // clamp: invalid slots produce garbage
        int kc = k < NN ? k : NN - 1;       // that is never read back
        float4 g = G4[ic], h = H4[kc];
        float f = g.x * h.x + g.y * h.y + g.z * h.z + g.w * h.w;
        float c = 0.f;
        if (t0 + tl != 0) c = sA[ic - 1] * sB[kc - 1];
        M = fmaf(c, M, f);
        vals[tl][tid] = f2bf(M);            // lanes contiguous -> conflict-free
    }
    __syncthreads();

    // write-out: rows i_lo..i_hi, each a contiguous k-run
    int i_lo = t0 + (o0 > 0 ? o0 : 0);
    int i_hi = (t0 + TSEG - 1) + (o_hi > 0 ? o_hi : 0);
    if (i_hi > NN - 1) i_hi = NN - 1;
    for (int i = i_lo; i <= i_hi; ++i) {
        int k_lo = i - o_hi;
        if (k_lo < t0) k_lo = t0;
        if (k_lo < 0) k_lo = 0;
        int k_hi = i - o0;
        if (k_hi > NN - 1) k_hi = NN - 1;
        if (i >= t0 + TSEG && k_hi > t0 + TSEG - 1) k_hi = t0 + TSEG - 1;
        int k = k_lo + tid;
        if (k <= k_hi) {
            int t = i < k ? i : k;
            int ddl = (i - k + (NN - 1)) - dd0;
            V[(size_t)i * NN + k] = vals[t - t0][ddl];
        }
    }
}

// ---- GEMM: out[b,i] = sum_k xb[b,k] * V[i][k] + bias[i]  (B^T-layout GEMM) ----
// 128x128 tile, BK=64, 4 waves (2x2), each wave 64x64 = 4x4 frags of 16x16x32 bf16 MFMA.
__global__ __launch_bounds__(256) void k_gemm(const unsigned short* __restrict__ A,
                                              const unsigned short* __restrict__ Bv,
                                              const float* __restrict__ bias,
                                              float* __restrict__ C) {
    __shared__ unsigned short lA[128 * 64];  // [row m][k] row-major, 128B rows
    __shared__ unsigned short lB[128 * 64];  // [row n(i)][k] row-major

    int bm = blockIdx.x;  // 0..7   (batch rows / 128)
    int bn = blockIdx.y;  // 0..31  (output cols / 128)
    int tid = threadIdx.x;
    int lane = tid & 63;
    int wid = tid >> 6;
    int wm = wid >> 1, wn = wid & 1;

    const unsigned short* aptr[4];
    const unsigned short* bptr[4];
#pragma unroll
    for (int c = 0; c < 4; ++c) {
        int ca = wid * 4 + c;
        int row = ca * 8 + (lane >> 3);
        int cole = (lane & 7) * 8;
        aptr[c] = A + ((size_t)(bm * 128 + row) * NN) + cole;
        bptr[c] = Bv + ((size_t)(bn * 128 + row) * NN) + cole;
    }

    f32x4 acc[4][4];
#pragma unroll
    for (int i = 0; i < 4; ++i)
#pragma unroll
        for (int j = 0; j < 4; ++j) acc[i][j] = (f32x4){0.f, 0.f, 0.f, 0.f};

    for (int kt = 0; kt < NN / 64; ++kt) {
#pragma unroll
        for (int c = 0; c < 4; ++c) {
            int ca = wid * 4 + c;
            __builtin_amdgcn_global_load_lds(
                (const __attribute__((address_space(1))) uint32_t*)(aptr[c]),
                (__attribute__((address_space(3))) uint32_t*)(&lA[ca * 512]), 16, 0, 0);
            __builtin_amdgcn_global_load_lds(
                (const __attribute__((address_space(1))) uint32_t*)(bptr[c]),
                (__attribute__((address_space(3))) uint32_t*)(&lB[ca * 512]), 16, 0, 0);
            aptr[c] += 64;
            bptr[c] += 64;
        }
        __syncthreads();
#pragma unroll
        for (int kk = 0; kk < 2; ++kk) {
            bf16x8 af[4], bf[4];
#pragma unroll
            for (int mf = 0; mf < 4; ++mf)
                af[mf] = *(const bf16x8*)&lA[(wm * 64 + mf * 16 + (lane & 15)) * 64 + kk * 32 + (lane >> 4) * 8];
#pragma unroll
            for (int nf = 0; nf < 4; ++nf)
                bf[nf] = *(const bf16x8*)&lB[(wn * 64 + nf * 16 + (lane & 15)) * 64 + kk * 32 + (lane >> 4) * 8];
#pragma unroll
            for (int mf = 0; mf < 4; ++mf)
#pragma unroll
                for (int nf = 0; nf < 4; ++nf)
                    acc[mf][nf] = __builtin_amdgcn_mfma_f32_16x16x32_bf16(af[mf], bf[nf], acc[mf][nf], 0, 0, 0);
        }
        __syncthreads();
    }

#pragma unroll
    for (int nf = 0; nf < 4; ++nf) {
        int col = bn * 128 + wn * 64 + nf * 16 + (lane & 15);
        float bv = bias[col];
#pragma unroll
        for (int mf = 0; mf < 4; ++mf) {
            f32x4 v = acc[mf][nf];
            int row0 = bm * 128 + wm * 64 + mf * 16 + (lane >> 4) * 4;
#pragma unroll
            for (int r = 0; r < 4; ++r)
                C[(size_t)(row0 + r) * NN + col] = v[r] + bv;
        }
    }
}

extern "C" void kernel_launch(void* const* d_in, const int* in_sizes, int n_in,
                              void* d_out, int out_size, void* d_ws, size_t ws_size,
                              hipStream_t stream) {
    (void)in_sizes; (void)n_in; (void)out_size; (void)ws_size;
    const float* x  = (const float*)d_in[0];
    const float* sA = (const float*)d_in[1];
    const float* sB = (const float*)d_in[2];
    const float* G  = (const float*)d_in[3];
    const float* H  = (const float*)d_in[4];
    const float* bias = (const float*)d_in[5];
    float* out = (float*)d_out;

    char* ws = (char*)d_ws;
    unsigned short* V  = (unsigned short*)ws;               // 33,554,432 B
    unsigned short* xb = (unsigned short*)(ws + 33554432);  // 8,388,608 B
    float4* G4 = (float4*)(ws + 41943040);                  // 65,536 B
    float4* H4 = (float4*)(ws + 42008576);                  // 65,536 B
    float2* seg = (float2*)(ws + 42074112);                 // 2,097,152 B
    float* carr = (float*)(ws + 44171264);                  // 1,048,576 B

    hipLaunchKernelGGL(k_prep, dim3(16), dim3(256), 0, stream, G, H, G4, H4);
    hipLaunchKernelGGL(k_convert, dim3((BATCH * NN / 4) / 256), dim3(256), 0, stream,
                       (const float4*)x, (ushort4*)xb);
    hipLaunchKernelGGL(k_pass1, dim3((NSEG * DPAD) / 256), dim3(256), 0, stream,
                       G4, H4, sA, sB, seg);
    hipLaunchKernelGGL(k_pass2, dim3(DPAD / 256), dim3(256), 0, stream, seg, carr);
    hipLaunchKernelGGL(k_pass3t, dim3(DPAD / DGRP, NN / TSEG), dim3(256), 0, stream,
                       G4, H4, sA, sB, carr, V);
    hipLaunchKernelGGL(k_gemm, dim3(BATCH / 128, NN / 128), dim3(256), 0, stream,
                       xb, V, bias, out);
}

// Round 3
// 232.828 us; speedup vs baseline: 1.2756x; 1.1161x over previous
//
#include <hip/hip_runtime.h>
#include <hip/hip_bf16.h>
#include <stdint.h>

#define NN 4096
#define BATCH 1024
#define SEG 128
#define NSEG 32
#define DPAD 8192
#define DGRP 256   // diagonals per pass3 block
#define TSEG 128   // steps per pass3 block (== SEG, matches carr granularity)

typedef __bf16 bf16x8 __attribute__((ext_vector_type(8)));
typedef float f32x4 __attribute__((ext_vector_type(4)));
typedef unsigned short u16x8 __attribute__((ext_vector_type(8)));

__device__ __forceinline__ unsigned short f2bf(float f) {
    uint32_t u = __builtin_bit_cast(uint32_t, f);
    uint32_t r = (u + 0x7FFFu + ((u >> 16) & 1u)) >> 16;
    return (unsigned short)r;
}

// ---- transpose G,H (R x N, R=4) into float4-per-position arrays ----
__global__ void k_prep(const float* __restrict__ G, const float* __restrict__ H,
                       float4* __restrict__ G4, float4* __restrict__ H4) {
    int p = blockIdx.x * 256 + threadIdx.x;
    if (p < NN) {
        G4[p] = make_float4(G[p], G[NN + p], G[2 * NN + p], G[3 * NN + p]);
        H4[p] = make_float4(H[p], H[NN + p], H[2 * NN + p], H[3 * NN + p]);
    }
}

// ---- convert x fp32 -> bf16 ----
__global__ void k_convert(const float4* __restrict__ x4, ushort4* __restrict__ xb4) {
    int t = blockIdx.x * 256 + threadIdx.x;  // BATCH*NN/4 threads exactly
    float4 a = x4[t];
    ushort4 o;
    o.x = f2bf(a.x); o.y = f2bf(a.y); o.z = f2bf(a.z); o.w = f2bf(a.w);
    xb4[t] = o;
}

// ---- pass 1: per-(diagonal, segment) affine map (A = prod c, B = local sum) ----
// M[i,k] = f(i,k) + sA_i*sB_k*M[i-1,k-1]; along diag (i-k = o), step t.
__global__ void k_pass1(const float4* __restrict__ G4, const float4* __restrict__ H4,
                        const float* __restrict__ sA, const float* __restrict__ sB,
                        float2* __restrict__ seg) {
    int tid = blockIdx.x * 256 + threadIdx.x;
    int s = tid >> 13;        // segment index 0..31
    int dd = tid & (DPAD - 1);
    int o = dd - (NN - 1);
    if (o > NN - 1) return;
    int ao = o < 0 ? -o : o;
    int L = NN - ao;
    int nseg = (L + SEG - 1) >> 7;
    if (s >= nseg) return;
    int t0 = s * SEG;
    int tend = t0 + SEG; if (tend > L) tend = L;
    float M = 0.f, Aacc = 1.f;
    for (int t = t0; t < tend; ++t) {
        int i = (o >= 0) ? (t + o) : t;
        int k = (o >= 0) ? t : (t - o);
        float4 g = G4[i], h = H4[k];
        float f = g.x * h.x + g.y * h.y + g.z * h.z + g.w * h.w;
        float c = (t == 0) ? 0.f : sA[i - 1] * sB[k - 1];
        M = fmaf(c, M, f);
        Aacc *= c;
    }
    seg[s * DPAD + dd] = make_float2(Aacc, M);
}

// ---- pass 2: scan affine maps along each diagonal -> carry-in per segment ----
__global__ void k_pass2(const float2* __restrict__ seg, float* __restrict__ carr) {
    int dd = blockIdx.x * 256 + threadIdx.x;
    if (dd >= DPAD) return;
    int o = dd - (NN - 1);
    if (o > NN - 1) return;
    int ao = o < 0 ? -o : o;
    int L = NN - ao;
    int nseg = (L + SEG - 1) >> 7;
    float Min = 0.f;
    for (int s = 0; s < nseg; ++s) {
        carr[s * DPAD + dd] = Min;
        float2 ab = seg[s * DPAD + dd];
        Min = fmaf(ab.x, Min, ab.y);
    }
}

// ---- pass 3 (tiled): recurrence into LDS, 16B-vectorized coalesced V write ----
// Block = 256 diagonals x 128 steps parallelogram. Each output row i intersects
// the parallelogram in a contiguous k-run (<=256 elems). Write-out: 8 rows per
// iteration, 32 threads/row, each thread packs 8 elems (one aligned 16B chunk).
__global__ __launch_bounds__(256) void k_pass3t(
        const float4* __restrict__ G4, const float4* __restrict__ H4,
        const float* __restrict__ sA, const float* __restrict__ sB,
        const float* __restrict__ carr, unsigned short* __restrict__ V) {
    __shared__ unsigned short vals[TSEG][DGRP];  // [t_local][dd_local] = 64 KB

    int dg = blockIdx.x;        // 0..31 diagonal group
    int sg = blockIdx.y;        // 0..31 step segment
    int dd0 = dg * DGRP;
    int t0 = sg * TSEG;
    int o0 = dd0 - (NN - 1);
    int o_hi = o0 + DGRP - 1;

    // early-exit fully-empty blocks: longest diagonal in group
    int minabs = (o0 >= 0) ? o0 : ((o_hi < 0) ? -o_hi : 0);
    if (t0 >= NN - minabs) return;

    int tid = threadIdx.x;
    int dd = dd0 + tid;
    int o = dd - (NN - 1);
    int i0 = t0 + (o > 0 ? o : 0);
    int k0 = t0 - (o < 0 ? o : 0);

    float M = carr[sg * DPAD + dd];
#pragma unroll 4
    for (int tl = 0; tl < TSEG; ++tl) {
        int i = i0 + tl, k = k0 + tl;
        int ic = i < NN ? i : NN - 1;       // clamp: invalid slots produce garbage
        int kc = k < NN ? k : NN - 1;       // that is never read back
        float4 g = G4[ic], h = H4[kc];
        float f = g.x * h.x + g.y * h.y + g.z * h.z + g.w * h.w;
        float c = 0.f;
        if (t0 + tl != 0) c = sA[ic - 1] * sB[kc - 1];
        M = fmaf(c, M, f);
        vals[tl][tid] = f2bf(M);            // lanes contiguous -> conflict-free
    }
    __syncthreads();

    // write-out
    int i_lo = t0 + (o0 > 0 ? o0 : 0);
    int i_hi = (t0 + TSEG - 1) + (o_hi > 0 ? o_hi : 0);
    if (i_hi > NN - 1) i_hi = NN - 1;
    int nrows = i_hi - i_lo + 1;
    int row_sub = tid >> 5;   // 0..7
    int csub = tid & 31;      // chunk lane within row

    for (int rb = 0; rb < nrows; rb += 8) {
        int i = i_lo + rb + row_sub;
        if (i > i_hi) continue;
        int k_lo = i - o_hi;
        if (k_lo < t0) k_lo = t0;
        if (k_lo < 0) k_lo = 0;
        int k_hi = i - o0;
        if (k_hi > NN - 1) k_hi = NN - 1;
        if (i >= t0 + TSEG && k_hi > t0 + TSEG - 1) k_hi = t0 + TSEG - 1;
        int cbase = k_lo >> 3;
        int clast = k_hi >> 3;
        for (int cc = cbase + csub; cc <= clast; cc += 32) {
            int kb = cc << 3;
            if (kb >= k_lo && kb + 7 <= k_hi) {
                u16x8 v;
#pragma unroll
                for (int j = 0; j < 8; ++j) {
                    int k = kb + j;
                    int t = k < i ? k : i;
                    int ddl = (i - k + (NN - 1)) - dd0;
                    v[j] = vals[t - t0][ddl];
                }
                *(u16x8*)(&V[(size_t)i * NN + kb]) = v;
            } else {
#pragma unroll
                for (int j = 0; j < 8; ++j) {
                    int k = kb + j;
                    if (k < k_lo || k > k_hi) continue;
                    int t = k < i ? k : i;
                    int ddl = (i - k + (NN - 1)) - dd0;
                    V[(size_t)i * NN + k] = vals[t - t0][ddl];
                }
            }
        }
    }
}

// ---- GEMM: out[b,i] = sum_k xb[b,k] * V[i][k] + bias[i]  (B^T-layout GEMM) ----
// 128x128 tile, BK=64, 4 waves (2x2), each wave 64x64 = 4x4 frags of 16x16x32 bf16 MFMA.
__global__ __launch_bounds__(256) void k_gemm(const unsigned short* __restrict__ A,
                                              const unsigned short* __restrict__ Bv,
                                              const float* __restrict__ bias,
                                              float* __restrict__ C) {
    __shared__ unsigned short lA[128 * 64];  // [row m][k] row-major, 128B rows
    __shared__ unsigned short lB[128 * 64];  // [row n(i)][k] row-major

    int bm = blockIdx.x;  // 0..7   (batch rows / 128)
    int bn = blockIdx.y;  // 0..31  (output cols / 128)
    int tid = threadIdx.x;
    int lane = tid & 63;
    int wid = tid >> 6;
    int wm = wid >> 1, wn = wid & 1;

    const unsigned short* aptr[4];
    const unsigned short* bptr[4];
#pragma unroll
    for (int c = 0; c < 4; ++c) {
        int ca = wid * 4 + c;
        int row = ca * 8 + (lane >> 3);
        int cole = (lane & 7) * 8;
        aptr[c] = A + ((size_t)(bm * 128 + row) * NN) + cole;
        bptr[c] = Bv + ((size_t)(bn * 128 + row) * NN) + cole;
    }

    f32x4 acc[4][4];
#pragma unroll
    for (int i = 0; i < 4; ++i)
#pragma unroll
        for (int j = 0; j < 4; ++j) acc[i][j] = (f32x4){0.f, 0.f, 0.f, 0.f};

    for (int kt = 0; kt < NN / 64; ++kt) {
#pragma unroll
        for (int c = 0; c < 4; ++c) {
            int ca = wid * 4 + c;
            __builtin_amdgcn_global_load_lds(
                (const __attribute__((address_space(1))) uint32_t*)(aptr[c]),
                (__attribute__((address_space(3))) uint32_t*)(&lA[ca * 512]), 16, 0, 0);
            __builtin_amdgcn_global_load_lds(
                (const __attribute__((address_space(1))) uint32_t*)(bptr[c]),
                (__attribute__((address_space(3))) uint32_t*)(&lB[ca * 512]), 16, 0, 0);
            aptr[c] += 64;
            bptr[c] += 64;
        }
        __syncthreads();
#pragma unroll
        for (int kk = 0; kk < 2; ++kk) {
            bf16x8 af[4], bf[4];
#pragma unroll
            for (int mf = 0; mf < 4; ++mf)
                af[mf] = *(const bf16x8*)&lA[(wm * 64 + mf * 16 + (lane & 15)) * 64 + kk * 32 + (lane >> 4) * 8];
#pragma unroll
            for (int nf = 0; nf < 4; ++nf)
                bf[nf] = *(const bf16x8*)&lB[(wn * 64 + nf * 16 + (lane & 15)) * 64 + kk * 32 + (lane >> 4) * 8];
#pragma unroll
            for (int mf = 0; mf < 4; ++mf)
#pragma unroll
                for (int nf = 0; nf < 4; ++nf)
                    acc[mf][nf] = __builtin_amdgcn_mfma_f32_16x16x32_bf16(af[mf], bf[nf], acc[mf][nf], 0, 0, 0);
        }
        __syncthreads();
    }

#pragma unroll
    for (int nf = 0; nf < 4; ++nf) {
        int col = bn * 128 + wn * 64 + nf * 16 + (lane & 15);
        float bv = bias[col];
#pragma unroll
        for (int mf = 0; mf < 4; ++mf) {
            f32x4 v = acc[mf][nf];
            int row0 = bm * 128 + wm * 64 + mf * 16 + (lane >> 4) * 4;
#pragma unroll
            for (int r = 0; r < 4; ++r)
                C[(size_t)(row0 + r) * NN + col] = v[r] + bv;
        }
    }
}

extern "C" void kernel_launch(void* const* d_in, const int* in_sizes, int n_in,
                              void* d_out, int out_size, void* d_ws, size_t ws_size,
                              hipStream_t stream) {
    (void)in_sizes; (void)n_in; (void)out_size; (void)ws_size;
    const float* x  = (const float*)d_in[0];
    const float* sA = (const float*)d_in[1];
    const float* sB = (const float*)d_in[2];
    const float* G  = (const float*)d_in[3];
    const float* H  = (const float*)d_in[4];
    const float* bias = (const float*)d_in[5];
    float* out = (float*)d_out;

    char* ws = (char*)d_ws;
    unsigned short* V  = (unsigned short*)ws;               // 33,554,432 B
    unsigned short* xb = (unsigned short*)(ws + 33554432);  // 8,388,608 B
    float4* G4 = (float4*)(ws + 41943040);                  // 65,536 B
    float4* H4 = (float4*)(ws + 42008576);                  // 65,536 B
    float2* seg = (float2*)(ws + 42074112);                 // 2,097,152 B
    float* carr = (float*)(ws + 44171264);                  // 1,048,576 B

    hipLaunchKernelGGL(k_prep, dim3(16), dim3(256), 0, stream, G, H, G4, H4);
    hipLaunchKernelGGL(k_convert, dim3((BATCH * NN / 4) / 256), dim3(256), 0, stream,
                       (const float4*)x, (ushort4*)xb);
    hipLaunchKernelGGL(k_pass1, dim3((NSEG * DPAD) / 256), dim3(256), 0, stream,
                       G4, H4, sA, sB, seg);
    hipLaunchKernelGGL(k_pass2, dim3(DPAD / 256), dim3(256), 0, stream, seg, carr);
    hipLaunchKernelGGL(k_pass3t, dim3(DPAD / DGRP, NN / TSEG), dim3(256), 0, stream,
                       G4, H4, sA, sB, carr, V);
    hipLaunchKernelGGL(k_gemm, dim3(BATCH / 128, NN / 128), dim3(256), 0, stream,
                       xb, V, bias, out);
}

// Round 4
// 216.496 us; speedup vs baseline: 1.3718x; 1.0754x over previous
//
#include <hip/hip_runtime.h>
#include <hip/hip_bf16.h>
#include <stdint.h>

#define NN 4096
#define BATCH 1024
#define SEG 64          // carry granularity (steps)
#define NSEG 64
#define DPAD 8192
#define DGRP 128        // diagonals per pass3 block
#define TSEG 128        // steps per pass3 block (2 x SEG)
#define P3ROWS 255      // TSEG + DGRP - 1

typedef __bf16 bf16x8 __attribute__((ext_vector_type(8)));
typedef float f32x4 __attribute__((ext_vector_type(4)));

__device__ __forceinline__ unsigned short f2bf(float f) {
    uint32_t u = __builtin_bit_cast(uint32_t, f);
    uint32_t r = (u + 0x7FFFu + ((u >> 16) & 1u)) >> 16;
    return (unsigned short)r;
}

// ---- transpose G,H (R x N, R=4) into float4-per-position arrays ----
__global__ void k_prep(const float* __restrict__ G, const float* __restrict__ H,
                       float4* __restrict__ G4, float4* __restrict__ H4) {
    int p = blockIdx.x * 256 + threadIdx.x;
    if (p < NN) {
        G4[p] = make_float4(G[p], G[NN + p], G[2 * NN + p], G[3 * NN + p]);
        H4[p] = make_float4(H[p], H[NN + p], H[2 * NN + p], H[3 * NN + p]);
    }
}

// ---- convert x fp32 -> bf16 ----
__global__ void k_convert(const float4* __restrict__ x4, ushort4* __restrict__ xb4) {
    int t = blockIdx.x * 256 + threadIdx.x;  // BATCH*NN/4 threads exactly
    float4 a = x4[t];
    ushort4 o;
    o.x = f2bf(a.x); o.y = f2bf(a.y); o.z = f2bf(a.z); o.w = f2bf(a.w);
    xb4[t] = o;
}

// ---- pass 1: per-(diagonal, 64-step segment) affine map ----
__global__ void k_pass1(const float4* __restrict__ G4, const float4* __restrict__ H4,
                        const float* __restrict__ sA, const float* __restrict__ sB,
                        float2* __restrict__ seg) {
    int tid = blockIdx.x * 256 + threadIdx.x;
    int s = tid >> 13;        // segment index 0..63
    int dd = tid & (DPAD - 1);
    int o = dd - (NN - 1);
    if (o > NN - 1) return;
    int ao = o < 0 ? -o : o;
    int L = NN - ao;
    int nseg = (L + SEG - 1) >> 6;
    if (s >= nseg) return;
    int t0 = s * SEG;
    int tend = t0 + SEG; if (tend > L) tend = L;
    float M = 0.f, Aacc = 1.f;
    for (int t = t0; t < tend; ++t) {
        int i = (o >= 0) ? (t + o) : t;
        int k = (o >= 0) ? t : (t - o);
        float4 g = G4[i], h = H4[k];
        float f = g.x * h.x + g.y * h.y + g.z * h.z + g.w * h.w;
        float c = (t == 0) ? 0.f : sA[i - 1] * sB[k - 1];
        M = fmaf(c, M, f);
        Aacc *= c;
    }
    seg[(size_t)s * DPAD + dd] = make_float2(Aacc, M);
}

// ---- pass 2: scan affine maps along each diagonal -> carry-in per segment ----
__global__ void k_pass2(const float2* __restrict__ seg, float* __restrict__ carr) {
    int dd = blockIdx.x * 256 + threadIdx.x;
    if (dd >= DPAD) return;
    int o = dd - (NN - 1);
    if (o > NN - 1) return;
    int ao = o < 0 ? -o : o;
    int L = NN - ao;
    int nseg = (L + SEG - 1) >> 6;
    float Min = 0.f;
    for (int s = 0; s < nseg; ++s) {
        carr[(size_t)s * DPAD + dd] = Min;
        float2 ab = seg[(size_t)s * DPAD + dd];
        Min = fmaf(ab.x, Min, ab.y);
    }
}

// ---- pass 3: recurrence into SHEARED LDS (row rr = i - i_lo, col = k mod 128,
// XOR-swizzled), then vectorized contiguous write-out per output row.
__global__ __launch_bounds__(256) void k_pass3t(
        const float4* __restrict__ G4, const float4* __restrict__ H4,
        const float* __restrict__ sA, const float* __restrict__ sB,
        const float* __restrict__ carr, unsigned short* __restrict__ V) {
    __shared__ unsigned short vals[P3ROWS * DGRP];  // 65,280 B

    int dg = blockIdx.x;   // 0..63 diagonal group
    int sg = blockIdx.y;   // 0..31 step tile (2 SEGs)
    int dd0 = dg * DGRP;
    int t0 = sg * TSEG;
    int o0 = dd0 - (NN - 1);
    int o_hi = o0 + DGRP - 1;

    int minabs = (o0 >= 0) ? o0 : ((o_hi < 0) ? -o_hi : 0);
    if (t0 >= NN - minabs) return;

    int tid = threadIdx.x;
    int tidd = tid & 127;
    int half = tid >> 7;
    int dd = dd0 + tidd;
    int o = dd - (NN - 1);
    int i_lo = t0 + (o0 > 0 ? o0 : 0);

    int ts = t0 + half * SEG;
    int ib = ts + (o > 0 ? o : 0);
    int kb0 = ts - (o < 0 ? o : 0);

    float M = carr[(size_t)(sg * 2 + half) * DPAD + dd];
#pragma unroll 4
    for (int tl = 0; tl < SEG; ++tl) {
        int i = ib + tl, k = kb0 + tl;
        int ic = i < NN ? i : NN - 1;       // clamped: garbage lanes fill only
        int kc = k < NN ? k : NN - 1;       // unused mod-128 residues (never read)
        float4 g = G4[ic], h = H4[kc];
        float f = g.x * h.x + g.y * h.y + g.z * h.z + g.w * h.w;
        float c = 0.f;
        if (ts + tl != 0) c = sA[ic - 1] * sB[kc - 1];
        M = fmaf(c, M, f);
        int rr = i - i_lo;                       // 0..254
        int csw = (k & 127) ^ ((rr & 31) << 2);  // swizzle: <=4-way write alias
        vals[rr * DGRP + csw] = f2bf(M);
    }
    __syncthreads();

    int i_hi = (t0 + TSEG - 1) + (o_hi > 0 ? o_hi : 0);
    if (i_hi > NN - 1) i_hi = NN - 1;
    int nrows = i_hi - i_lo + 1;
    int row_sub = tid >> 5;   // 0..7
    int csub = tid & 31;      // 4-elem chunk lane within row

    for (int rb = 0; rb < nrows; rb += 8) {
        int i = i_lo + rb + row_sub;
        if (i > i_hi) continue;
        int k_lo = i - o_hi;
        if (k_lo < t0) k_lo = t0;
        if (k_lo < 0) k_lo = 0;
        int k_hi = i - o0;
        if (k_hi > NN - 1) k_hi = NN - 1;
        if (i >= t0 + TSEG && k_hi > t0 + TSEG - 1) k_hi = t0 + TSEG - 1;
        int rr = i - i_lo;
        int swz = (rr & 31) << 2;
        size_t rowbase = (size_t)i * NN;
        int cb_first = k_lo >> 2, cb_last = k_hi >> 2;
        for (int cc = cb_first + csub; cc <= cb_last; cc += 32) {
            int kb = cc << 2;
            if (kb >= k_lo && kb + 3 <= k_hi) {
                int c0 = (kb & 127) ^ swz;       // chunk stays contiguous (swz bits>=2)
                ushort4 v = *(const ushort4*)&vals[rr * DGRP + c0];
                *(ushort4*)&V[rowbase + kb] = v;
            } else {
#pragma unroll
                for (int j = 0; j < 4; ++j) {
                    int k = kb + j;
                    if (k < k_lo || k > k_hi) continue;
                    int c = (k & 127) ^ swz;
                    V[rowbase + k] = vals[rr * DGRP + c];
                }
            }
        }
    }
}

// ---- GEMM: out[b,i] = sum_k xb[b,k] * V[i][k] + bias[i]  (B^T-layout) ----
// BM=64 x BN=128 tile, BK=64, 512 blocks (2/CU), 4 waves (2x2), wave 32x64.
// 2-phase double-buffered pipeline: STAGE(next) issued before compute(cur).
__global__ __launch_bounds__(256) void k_gemm(const unsigned short* __restrict__ A,
                                              const unsigned short* __restrict__ Bv,
                                              const float* __restrict__ bias,
                                              float* __restrict__ C) {
    __shared__ unsigned short lA[2][64 * 64];    // 16 KB
    __shared__ unsigned short lB[2][128 * 64];   // 32 KB

    // bijective XCD swizzle (512 % 8 == 0): XCD c gets bn in [c*4, c*4+4)
    int flat = blockIdx.y * 16 + blockIdx.x;
    int wg = (flat & 7) * 64 + (flat >> 3);
    int bm = wg & 15;
    int bn = wg >> 4;

    int tid = threadIdx.x;
    int lane = tid & 63;
    int wid = tid >> 6;
    int wm = wid >> 1, wn = wid & 1;

    const unsigned short* aptr[2];
    const unsigned short* bptr[4];
#pragma unroll
    for (int c = 0; c < 2; ++c) {
        int u = c * 256 + tid;
        aptr[c] = A + ((size_t)(bm * 64 + (u >> 3)) * NN) + (u & 7) * 8;
    }
#pragma unroll
    for (int c = 0; c < 4; ++c) {
        int u = c * 256 + tid;
        bptr[c] = Bv + ((size_t)(bn * 128 + (u >> 3)) * NN) + (u & 7) * 8;
    }

    f32x4 acc[2][4];
#pragma unroll
    for (int i = 0; i < 2; ++i)
#pragma unroll
        for (int j = 0; j < 4; ++j) acc[i][j] = (f32x4){0.f, 0.f, 0.f, 0.f};

#define STAGE(buf)                                                                   \
    do {                                                                             \
        _Pragma("unroll") for (int c = 0; c < 2; ++c) {                              \
            __builtin_amdgcn_global_load_lds(                                        \
                (const __attribute__((address_space(1))) uint32_t*)(aptr[c]),        \
                (__attribute__((address_space(3))) uint32_t*)(&lA[buf][(c * 256 + tid) * 8]), \
                16, 0, 0);                                                           \
            aptr[c] += 64;                                                           \
        }                                                                            \
        _Pragma("unroll") for (int c = 0; c < 4; ++c) {                              \
            __builtin_amdgcn_global_load_lds(                                        \
                (const __attribute__((address_space(1))) uint32_t*)(bptr[c]),        \
                (__attribute__((address_space(3))) uint32_t*)(&lB[buf][(c * 256 + tid) * 8]), \
                16, 0, 0);                                                           \
            bptr[c] += 64;                                                           \
        }                                                                            \
    } while (0)

#define COMPUTE(buf)                                                                 \
    do {                                                                             \
        _Pragma("unroll") for (int kk = 0; kk < 2; ++kk) {                           \
            bf16x8 af[2], bfr[4];                                                    \
            _Pragma("unroll") for (int mf = 0; mf < 2; ++mf)                         \
                af[mf] = *(const bf16x8*)&lA[buf][(wm * 32 + mf * 16 + (lane & 15)) * 64 + kk * 32 + (lane >> 4) * 8]; \
            _Pragma("unroll") for (int nf = 0; nf < 4; ++nf)                         \
                bfr[nf] = *(const bf16x8*)&lB[buf][(wn * 64 + nf * 16 + (lane & 15)) * 64 + kk * 32 + (lane >> 4) * 8]; \
            _Pragma("unroll") for (int mf = 0; mf < 2; ++mf)                         \
                _Pragma("unroll") for (int nf = 0; nf < 4; ++nf)                     \
                    acc[mf][nf] = __builtin_amdgcn_mfma_f32_16x16x32_bf16(af[mf], bfr[nf], acc[mf][nf], 0, 0, 0); \
        }                                                                            \
    } while (0)

    STAGE(0);
    __syncthreads();       // drain prologue loads
    int cur = 0;
    for (int kt = 0; kt < NN / 64 - 1; ++kt) {
        STAGE(cur ^ 1);    // issue next tile's loads (in flight during compute)
        COMPUTE(cur);
        __syncthreads();   // waves done reading cur; next-tile loads drained
        cur ^= 1;
    }
    COMPUTE(cur);
#undef STAGE
#undef COMPUTE

    // epilogue: D frag col = lane&15, row = (lane>>4)*4 + r
#pragma unroll
    for (int nf = 0; nf < 4; ++nf) {
        int col = bn * 128 + wn * 64 + nf * 16 + (lane & 15);
        float bv = bias[col];
#pragma unroll
        for (int mf = 0; mf < 2; ++mf) {
            f32x4 v = acc[mf][nf];
            int row0 = bm * 64 + wm * 32 + mf * 16 + (lane >> 4) * 4;
#pragma unroll
            for (int r = 0; r < 4; ++r)
                C[(size_t)(row0 + r) * NN + col] = v[r] + bv;
        }
    }
}

extern "C" void kernel_launch(void* const* d_in, const int* in_sizes, int n_in,
                              void* d_out, int out_size, void* d_ws, size_t ws_size,
                              hipStream_t stream) {
    (void)in_sizes; (void)n_in; (void)out_size; (void)ws_size;
    const float* x  = (const float*)d_in[0];
    const float* sA = (const float*)d_in[1];
    const float* sB = (const float*)d_in[2];
    const float* G  = (const float*)d_in[3];
    const float* H  = (const float*)d_in[4];
    const float* bias = (const float*)d_in[5];
    float* out = (float*)d_out;

    char* ws = (char*)d_ws;
    unsigned short* V  = (unsigned short*)ws;               // 33,554,432 B
    // seg is ALIASED over V's first 4 MB: seg is dead after pass2; V written in pass3.
    float2* seg = (float2*)ws;                              // 4,194,304 B (aliased)
    unsigned short* xb = (unsigned short*)(ws + 33554432);  // 8,388,608 B
    float4* G4 = (float4*)(ws + 41943040);                  // 65,536 B
    float4* H4 = (float4*)(ws + 42008576);                  // 65,536 B
    float* carr = (float*)(ws + 42074112);                  // 2,097,152 B -> total 44.2 MB

    hipLaunchKernelGGL(k_prep, dim3(16), dim3(256), 0, stream, G, H, G4, H4);
    hipLaunchKernelGGL(k_convert, dim3((BATCH * NN / 4) / 256), dim3(256), 0, stream,
                       (const float4*)x, (ushort4*)xb);
    hipLaunchKernelGGL(k_pass1, dim3((NSEG * DPAD) / 256), dim3(256), 0, stream,
                       G4, H4, sA, sB, seg);
    hipLaunchKernelGGL(k_pass2, dim3(DPAD / 256), dim3(256), 0, stream, seg, carr);
    hipLaunchKernelGGL(k_pass3t, dim3(DPAD / DGRP, NN / TSEG), dim3(256), 0, stream,
                       G4, H4, sA, sB, carr, V);
    hipLaunchKernelGGL(k_gemm, dim3(BATCH / 64, NN / 128), dim3(256), 0, stream,
                       xb, V, bias, out);
}

// Round 6
// 205.094 us; speedup vs baseline: 1.4480x; 1.0556x over previous
//
#include <hip/hip_runtime.h>
#include <hip/hip_bf16.h>
#include <stdint.h>

#define NN 4096
#define BATCH 1024
#define SEG 64          // carry granularity (steps)
#define NSEG 64
#define DPAD 8192
#define DGRP 128        // diagonals per pass3 block
#define TSEG 128        // steps per pass3 block (2 x SEG)
#define P3ROWS 255      // TSEG + DGRP - 1

#define WS_PART_OFF 44171264u
#define WS_SPLITK_NEED (WS_PART_OFF + (size_t)BATCH * NN * 4)

typedef __bf16 bf16x8 __attribute__((ext_vector_type(8)));
typedef float f32x4 __attribute__((ext_vector_type(4)));

__device__ __forceinline__ unsigned short f2bf(float f) {
    uint32_t u = __builtin_bit_cast(uint32_t, f);
    uint32_t r = (u + 0x7FFFu + ((u >> 16) & 1u)) >> 16;
    return (unsigned short)r;
}

// ---- transpose G,H (R x N, R=4) into float4-per-position arrays ----
__global__ void k_prep(const float* __restrict__ G, const float* __restrict__ H,
                       float4* __restrict__ G4, float4* __restrict__ H4) {
    int p = blockIdx.x * 256 + threadIdx.x;
    if (p < NN) {
        G4[p] = make_float4(G[p], G[NN + p], G[2 * NN + p], G[3 * NN + p]);
        H4[p] = make_float4(H[p], H[NN + p], H[2 * NN + p], H[3 * NN + p]);
    }
}

// ---- convert x fp32 -> bf16 ----
__global__ void k_convert(const float4* __restrict__ x4, ushort4* __restrict__ xb4) {
    int t = blockIdx.x * 256 + threadIdx.x;
    float4 a = x4[t];
    ushort4 o;
    o.x = f2bf(a.x); o.y = f2bf(a.y); o.z = f2bf(a.z); o.w = f2bf(a.w);
    xb4[t] = o;
}

// ---- pass 1: per-(diagonal, 64-step segment) affine map ----
__global__ void k_pass1(const float4* __restrict__ G4, const float4* __restrict__ H4,
                        const float* __restrict__ sA, const float* __restrict__ sB,
                        float2* __restrict__ seg) {
    int tid = blockIdx.x * 256 + threadIdx.x;
    int s = tid >> 13;
    int dd = tid & (DPAD - 1);
    int o = dd - (NN - 1);
    if (o > NN - 1) return;
    int ao = o < 0 ? -o : o;
    int L = NN - ao;
    int nseg = (L + SEG - 1) >> 6;
    if (s >= nseg) return;
    int t0 = s * SEG;
    int tend = t0 + SEG; if (tend > L) tend = L;
    float M = 0.f, Aacc = 1.f;
    for (int t = t0; t < tend; ++t) {
        int i = (o >= 0) ? (t + o) : t;
        int k = (o >= 0) ? t : (t - o);
        float4 g = G4[i], h = H4[k];
        float f = g.x * h.x + g.y * h.y + g.z * h.z + g.w * h.w;
        float c = (t == 0) ? 0.f : sA[i - 1] * sB[k - 1];
        M = fmaf(c, M, f);
        Aacc *= c;
    }
    seg[(size_t)s * DPAD + dd] = make_float2(Aacc, M);
}

// ---- pass 2: scan affine maps along each diagonal -> carry-in per segment ----
__global__ void k_pass2(const float2* __restrict__ seg, float* __restrict__ carr) {
    int dd = blockIdx.x * 256 + threadIdx.x;
    if (dd >= DPAD) return;
    int o = dd - (NN - 1);
    if (o > NN - 1) return;
    int ao = o < 0 ? -o : o;
    int L = NN - ao;
    int nseg = (L + SEG - 1) >> 6;
    float Min = 0.f;
    for (int s = 0; s < nseg; ++s) {
        carr[(size_t)s * DPAD + dd] = Min;
        float2 ab = seg[(size_t)s * DPAD + dd];
        Min = fmaf(ab.x, Min, ab.y);
    }
}

// ---- pass 3: recurrence into sheared/swizzled LDS, vectorized coalesced write ----
__global__ __launch_bounds__(256) void k_pass3t(
        const float4* __restrict__ G4, const float4* __restrict__ H4,
        const float* __restrict__ sA, const float* __restrict__ sB,
        const float* __restrict__ carr, unsigned short* __restrict__ V) {
    __shared__ unsigned short vals[P3ROWS * DGRP];

    int dg = blockIdx.x;
    int sg = blockIdx.y;
    int dd0 = dg * DGRP;
    int t0 = sg * TSEG;
    int o0 = dd0 - (NN - 1);
    int o_hi = o0 + DGRP - 1;

    int minabs = (o0 >= 0) ? o0 : ((o_hi < 0) ? -o_hi : 0);
    if (t0 >= NN - minabs) return;

    int tid = threadIdx.x;
    int tidd = tid & 127;
    int half = tid >> 7;
    int dd = dd0 + tidd;
    int o = dd - (NN - 1);
    int i_lo = t0 + (o0 > 0 ? o0 : 0);

    int ts = t0 + half * SEG;
    int ib = ts + (o > 0 ? o : 0);
    int kb0 = ts - (o < 0 ? o : 0);

    float M = carr[(size_t)(sg * 2 + half) * DPAD + dd];
#pragma unroll 4
    for (int tl = 0; tl < SEG; ++tl) {
        int i = ib + tl, k = kb0 + tl;
        int ic = i < NN ? i : NN - 1;
        int kc = k < NN ? k : NN - 1;
        float4 g = G4[ic], h = H4[kc];
        float f = g.x * h.x + g.y * h.y + g.z * h.z + g.w * h.w;
        float c = 0.f;
        if (ts + tl != 0) c = sA[ic - 1] * sB[kc - 1];
        M = fmaf(c, M, f);
        int rr = i - i_lo;
        int csw = (k & 127) ^ ((rr & 31) << 2);
        vals[rr * DGRP + csw] = f2bf(M);
    }
    __syncthreads();

    int i_hi = (t0 + TSEG - 1) + (o_hi > 0 ? o_hi : 0);
    if (i_hi > NN - 1) i_hi = NN - 1;
    int nrows = i_hi - i_lo + 1;
    int row_sub = tid >> 5;
    int csub = tid & 31;

    for (int rb = 0; rb < nrows; rb += 8) {
        int i = i_lo + rb + row_sub;
        if (i > i_hi) continue;
        int k_lo = i - o_hi;
        if (k_lo < t0) k_lo = t0;
        if (k_lo < 0) k_lo = 0;
        int k_hi = i - o0;
        if (k_hi > NN - 1) k_hi = NN - 1;
        if (i >= t0 + TSEG && k_hi > t0 + TSEG - 1) k_hi = t0 + TSEG - 1;
        int rr = i - i_lo;
        int swz = (rr & 31) << 2;
        size_t rowbase = (size_t)i * NN;
        int cb_first = k_lo >> 2, cb_last = k_hi >> 2;
        for (int cc = cb_first + csub; cc <= cb_last; cc += 32) {
            int kb = cc << 2;
            if (kb >= k_lo && kb + 3 <= k_hi) {
                int c0 = (kb & 127) ^ swz;
                ushort4 v = *(const ushort4*)&vals[rr * DGRP + c0];
                *(ushort4*)&V[rowbase + kb] = v;
            } else {
#pragma unroll
                for (int j = 0; j < 4; ++j) {
                    int k = kb + j;
                    if (k < k_lo || k > k_hi) continue;
                    int c = (k & 127) ^ swz;
                    V[rowbase + k] = vals[rr * DGRP + c];
                }
            }
        }
    }
}

// ---- split-K GEMM: m97 structure per block. 128x128 tile, BK=64, 4 waves of
// 64x64 (16 MFMA : 8 ds_read per kk), double-buffered 2-phase, K-half per z.
// z=0 -> C (no bias), z=1 -> partial. grid (8,32,2) = 512 blocks (2/CU).
__global__ __launch_bounds__(256) void k_gemm_sk(const unsigned short* __restrict__ A,
                                                 const unsigned short* __restrict__ Bv,
                                                 float* __restrict__ C,
                                                 float* __restrict__ part) {
    __shared__ unsigned short lA[2][128 * 64];   // 2 x 16 KB
    __shared__ unsigned short lB[2][128 * 64];   // 2 x 16 KB

    // bijective XCD swizzle over 512 blocks (512 % 8 == 0)
    int flat = (blockIdx.z * 32 + blockIdx.y) * 8 + blockIdx.x;
    int swz = (flat & 7) * 64 + (flat >> 3);
    int bz = swz & 1;
    int bm = (swz >> 1) & 7;
    int bn = swz >> 4;          // 16 consecutive swz share bn -> B-panel L2 reuse

    int tid = threadIdx.x;
    int lane = tid & 63;
    int wid = tid >> 6;
    int wm = wid >> 1, wn = wid & 1;

    int kbase = bz * (NN / 2);

    const unsigned short* aptr[4];
    const unsigned short* bptr[4];
#pragma unroll
    for (int c = 0; c < 4; ++c) {
        int u = c * 256 + tid;
        aptr[c] = A + ((size_t)(bm * 128 + (u >> 3)) * NN) + kbase + (u & 7) * 8;
        bptr[c] = Bv + ((size_t)(bn * 128 + (u >> 3)) * NN) + kbase + (u & 7) * 8;
    }

    f32x4 acc[4][4];
#pragma unroll
    for (int i = 0; i < 4; ++i)
#pragma unroll
        for (int j = 0; j < 4; ++j) acc[i][j] = (f32x4){0.f, 0.f, 0.f, 0.f};

#define STAGE_SK(buf)                                                                \
    do {                                                                             \
        _Pragma("unroll") for (int c = 0; c < 4; ++c) {                              \
            __builtin_amdgcn_global_load_lds(                                        \
                (const __attribute__((address_space(1))) uint32_t*)(aptr[c]),        \
                (__attribute__((address_space(3))) uint32_t*)(&lA[buf][(c * 256 + tid) * 8]), \
                16, 0, 0);                                                           \
            aptr[c] += 64;                                                           \
            __builtin_amdgcn_global_load_lds(                                        \
                (const __attribute__((address_space(1))) uint32_t*)(bptr[c]),        \
                (__attribute__((address_space(3))) uint32_t*)(&lB[buf][(c * 256 + tid) * 8]), \
                16, 0, 0);                                                           \
            bptr[c] += 64;                                                           \
        }                                                                            \
    } while (0)

#define COMPUTE_SK(buf)                                                              \
    do {                                                                             \
        _Pragma("unroll") for (int kk = 0; kk < 2; ++kk) {                           \
            bf16x8 af[4], bfr[4];                                                    \
            _Pragma("unroll") for (int mf = 0; mf < 4; ++mf)                         \
                af[mf] = *(const bf16x8*)&lA[buf][(wm * 64 + mf * 16 + (lane & 15)) * 64 + kk * 32 + (lane >> 4) * 8]; \
            _Pragma("unroll") for (int nf = 0; nf < 4; ++nf)                         \
                bfr[nf] = *(const bf16x8*)&lB[buf][(wn * 64 + nf * 16 + (lane & 15)) * 64 + kk * 32 + (lane >> 4) * 8]; \
            _Pragma("unroll") for (int mf = 0; mf < 4; ++mf)                         \
                _Pragma("unroll") for (int nf = 0; nf < 4; ++nf)                     \
                    acc[mf][nf] = __builtin_amdgcn_mfma_f32_16x16x32_bf16(af[mf], bfr[nf], acc[mf][nf], 0, 0, 0); \
        }                                                                            \
    } while (0)

    STAGE_SK(0);
    __syncthreads();
    int cur = 0;
    for (int kt = 0; kt < NN / 2 / 64 - 1; ++kt) {
        STAGE_SK(cur ^ 1);
        COMPUTE_SK(cur);
        __syncthreads();
        cur ^= 1;
    }
    COMPUTE_SK(cur);
#undef STAGE_SK
#undef COMPUTE_SK

    float* dst = bz ? part : C;
#pragma unroll
    for (int nf = 0; nf < 4; ++nf) {
        int col = bn * 128 + wn * 64 + nf * 16 + (lane & 15);
#pragma unroll
        for (int mf = 0; mf < 4; ++mf) {
            f32x4 v = acc[mf][nf];
            int row0 = bm * 128 + wm * 64 + mf * 16 + (lane >> 4) * 4;
#pragma unroll
            for (int r = 0; r < 4; ++r)
                dst[(size_t)(row0 + r) * NN + col] = v[r];
        }
    }
}

// ---- reduce: out = out(partial0) + partial1 + bias ----
__global__ void k_reduce(float4* __restrict__ C, const float4* __restrict__ part,
                         const float4* __restrict__ bias4) {
    int idx = blockIdx.x * 256 + threadIdx.x;   // BATCH*NN/4 exactly
    float4 p = C[idx];
    float4 q = part[idx];
    float4 b = bias4[idx & (NN / 4 - 1)];
    C[idx] = make_float4(p.x + q.x + b.x, p.y + q.y + b.y,
                         p.z + q.z + b.z, p.w + q.w + b.w);
}

// ---- fallback GEMM (R4 path): BM=64 x BN=128, used only if ws too small ----
__global__ __launch_bounds__(256) void k_gemm(const unsigned short* __restrict__ A,
                                              const unsigned short* __restrict__ Bv,
                                              const float* __restrict__ bias,
                                              float* __restrict__ C) {
    __shared__ unsigned short lA[2][64 * 64];
    __shared__ unsigned short lB[2][128 * 64];

    int flat = blockIdx.y * 16 + blockIdx.x;
    int wg = (flat & 7) * 64 + (flat >> 3);
    int bm = wg & 15;
    int bn = wg >> 4;

    int tid = threadIdx.x;
    int lane = tid & 63;
    int wid = tid >> 6;
    int wm = wid >> 1, wn = wid & 1;

    const unsigned short* aptr[2];
    const unsigned short* bptr[4];
#pragma unroll
    for (int c = 0; c < 2; ++c) {
        int u = c * 256 + tid;
        aptr[c] = A + ((size_t)(bm * 64 + (u >> 3)) * NN) + (u & 7) * 8;
    }
#pragma unroll
    for (int c = 0; c < 4; ++c) {
        int u = c * 256 + tid;
        bptr[c] = Bv + ((size_t)(bn * 128 + (u >> 3)) * NN) + (u & 7) * 8;
    }

    f32x4 acc[2][4];
#pragma unroll
    for (int i = 0; i < 2; ++i)
#pragma unroll
        for (int j = 0; j < 4; ++j) acc[i][j] = (f32x4){0.f, 0.f, 0.f, 0.f};

#define STAGE(buf)                                                                   \
    do {                                                                             \
        _Pragma("unroll") for (int c = 0; c < 2; ++c) {                              \
            __builtin_amdgcn_global_load_lds(                                        \
                (const __attribute__((address_space(1))) uint32_t*)(aptr[c]),        \
                (__attribute__((address_space(3))) uint32_t*)(&lA[buf][(c * 256 + tid) * 8]), \
                16, 0, 0);                                                           \
            aptr[c] += 64;                                                           \
        }                                                                            \
        _Pragma("unroll") for (int c = 0; c < 4; ++c) {                              \
            __builtin_amdgcn_global_load_lds(                                        \
                (const __attribute__((address_space(1))) uint32_t*)(bptr[c]),        \
                (__attribute__((address_space(3))) uint32_t*)(&lB[buf][(c * 256 + tid) * 8]), \
                16, 0, 0);                                                           \
            bptr[c] += 64;                                                           \
        }                                                                            \
    } while (0)

#define COMPUTE(buf)                                                                 \
    do {                                                                             \
        _Pragma("unroll") for (int kk = 0; kk < 2; ++kk) {                           \
            bf16x8 af[2], bfr[4];                                                    \
            _Pragma("unroll") for (int mf = 0; mf < 2; ++mf)                         \
                af[mf] = *(const bf16x8*)&lA[buf][(wm * 32 + mf * 16 + (lane & 15)) * 64 + kk * 32 + (lane >> 4) * 8]; \
            _Pragma("unroll") for (int nf = 0; nf < 4; ++nf)                         \
                bfr[nf] = *(const bf16x8*)&lB[buf][(wn * 64 + nf * 16 + (lane & 15)) * 64 + kk * 32 + (lane >> 4) * 8]; \
            _Pragma("unroll") for (int mf = 0; mf < 2; ++mf)                         \
                _Pragma("unroll") for (int nf = 0; nf < 4; ++nf)                     \
                    acc[mf][nf] = __builtin_amdgcn_mfma_f32_16x16x32_bf16(af[mf], bfr[nf], acc[mf][nf], 0, 0, 0); \
        }                                                                            \
    } while (0)

    STAGE(0);
    __syncthreads();
    int cur = 0;
    for (int kt = 0; kt < NN / 64 - 1; ++kt) {
        STAGE(cur ^ 1);
        COMPUTE(cur);
        __syncthreads();
        cur ^= 1;
    }
    COMPUTE(cur);
#undef STAGE
#undef COMPUTE

#pragma unroll
    for (int nf = 0; nf < 4; ++nf) {
        int col = bn * 128 + wn * 64 + nf * 16 + (lane & 15);
        float bv = bias[col];
#pragma unroll
        for (int mf = 0; mf < 2; ++mf) {
            f32x4 v = acc[mf][nf];
            int row0 = bm * 64 + wm * 32 + mf * 16 + (lane >> 4) * 4;
#pragma unroll
            for (int r = 0; r < 4; ++r)
                C[(size_t)(row0 + r) * NN + col] = v[r] + bv;
        }
    }
}

extern "C" void kernel_launch(void* const* d_in, const int* in_sizes, int n_in,
                              void* d_out, int out_size, void* d_ws, size_t ws_size,
                              hipStream_t stream) {
    (void)in_sizes; (void)n_in; (void)out_size;
    const float* x  = (const float*)d_in[0];
    const float* sA = (const float*)d_in[1];
    const float* sB = (const float*)d_in[2];
    const float* G  = (const float*)d_in[3];
    const float* H  = (const float*)d_in[4];
    const float* bias = (const float*)d_in[5];
    float* out = (float*)d_out;

    char* ws = (char*)d_ws;
    unsigned short* V  = (unsigned short*)ws;               // 33,554,432 B
    float2* seg = (float2*)ws;                              // 4 MB, aliased on V (dead before pass3)
    unsigned short* xb = (unsigned short*)(ws + 33554432);  // 8,388,608 B
    float4* G4 = (float4*)(ws + 41943040);                  // 65,536 B
    float4* H4 = (float4*)(ws + 42008576);                  // 65,536 B
    float* carr = (float*)(ws + 42074112);                  // 2,097,152 B
    float* part = (float*)(ws + WS_PART_OFF);               // 16,777,216 B (split-K only)

    hipLaunchKernelGGL(k_prep, dim3(16), dim3(256), 0, stream, G, H, G4, H4);
    hipLaunchKernelGGL(k_convert, dim3((BATCH * NN / 4) / 256), dim3(256), 0, stream,
                       (const float4*)x, (ushort4*)xb);
    hipLaunchKernelGGL(k_pass1, dim3((NSEG * DPAD) / 256), dim3(256), 0, stream,
                       G4, H4, sA, sB, seg);
    hipLaunchKernelGGL(k_pass2, dim3(DPAD / 256), dim3(256), 0, stream, seg, carr);
    hipLaunchKernelGGL(k_pass3t, dim3(DPAD / DGRP, NN / TSEG), dim3(256), 0, stream,
                       G4, H4, sA, sB, carr, V);

    if (ws_size >= WS_SPLITK_NEED) {
        hipLaunchKernelGGL(k_gemm_sk, dim3(8, 32, 2), dim3(256), 0, stream,
                           xb, V, out, part);
        hipLaunchKernelGGL(k_reduce, dim3((BATCH * NN / 4) / 256), dim3(256), 0, stream,
                           (float4*)out, (const float4*)part, (const float4*)bias);
    } else {
        hipLaunchKernelGGL(k_gemm, dim3(BATCH / 64, NN / 128), dim3(256), 0, stream,
                           xb, V, bias, out);
    }
}

// Round 7
// 177.174 us; speedup vs baseline: 1.6762x; 1.1576x over previous
//
#include <hip/hip_runtime.h>
#include <hip/hip_bf16.h>
#include <stdint.h>

#define NN 4096
#define BATCH 1024
#define SEG 64          // carry granularity (steps)
#define NSEG 64
#define DPAD 8192
#define DGRP 128        // diagonals per pass3 block (sign-pure since NN-1 = 4095 ≡ 127 mod 128)
#define TSEG 64         // steps per pass3 block (== SEG)

#define WS_PART_OFF 44171264u
#define WS_SPLITK_NEED (WS_PART_OFF + (size_t)BATCH * NN * 4)

typedef __bf16 bf16x8 __attribute__((ext_vector_type(8)));
typedef float f32x4 __attribute__((ext_vector_type(4)));

__device__ __forceinline__ unsigned short f2bf(float f) {
    uint32_t u = __builtin_bit_cast(uint32_t, f);
    uint32_t r = (u + 0x7FFFu + ((u >> 16) & 1u)) >> 16;
    return (unsigned short)r;
}

// ---- transpose G,H (R x N, R=4) into float4-per-position arrays ----
__global__ void k_prep(const float* __restrict__ G, const float* __restrict__ H,
                       float4* __restrict__ G4, float4* __restrict__ H4) {
    int p = blockIdx.x * 256 + threadIdx.x;
    if (p < NN) {
        G4[p] = make_float4(G[p], G[NN + p], G[2 * NN + p], G[3 * NN + p]);
        H4[p] = make_float4(H[p], H[NN + p], H[2 * NN + p], H[3 * NN + p]);
    }
}

// ---- convert x fp32 -> bf16 ----
__global__ void k_convert(const float4* __restrict__ x4, ushort4* __restrict__ xb4) {
    int t = blockIdx.x * 256 + threadIdx.x;
    float4 a = x4[t];
    ushort4 o;
    o.x = f2bf(a.x); o.y = f2bf(a.y); o.z = f2bf(a.z); o.w = f2bf(a.w);
    xb4[t] = o;
}

// ---- pass 1: per-(diagonal, 64-step segment) affine map ----
__global__ void k_pass1(const float4* __restrict__ G4, const float4* __restrict__ H4,
                        const float* __restrict__ sA, const float* __restrict__ sB,
                        float2* __restrict__ seg) {
    int tid = blockIdx.x * 256 + threadIdx.x;
    int s = tid >> 13;
    int dd = tid & (DPAD - 1);
    int o = dd - (NN - 1);
    if (o > NN - 1) return;
    int ao = o < 0 ? -o : o;
    int L = NN - ao;
    int nseg = (L + SEG - 1) >> 6;
    if (s >= nseg) return;
    int t0 = s * SEG;
    int tend = t0 + SEG; if (tend > L) tend = L;
    float M = 0.f, Aacc = 1.f;
    for (int t = t0; t < tend; ++t) {
        int i = (o >= 0) ? (t + o) : t;
        int k = (o >= 0) ? t : (t - o);
        float4 g = G4[i], h = H4[k];
        float f = g.x * h.x + g.y * h.y + g.z * h.z + g.w * h.w;
        float c = (t == 0) ? 0.f : sA[i - 1] * sB[k - 1];
        M = fmaf(c, M, f);
        Aacc *= c;
    }
    seg[(size_t)s * DPAD + dd] = make_float2(Aacc, M);
}

// ---- pass 2: scan affine maps along each diagonal -> carry-in per segment ----
__global__ void k_pass2(const float2* __restrict__ seg, float* __restrict__ carr) {
    int dd = blockIdx.x * 256 + threadIdx.x;
    if (dd >= DPAD) return;
    int o = dd - (NN - 1);
    if (o > NN - 1) return;
    int ao = o < 0 ? -o : o;
    int L = NN - ao;
    int nseg = (L + SEG - 1) >> 6;
    float Min = 0.f;
    for (int s = 0; s < nseg; ++s) {
        carr[(size_t)s * DPAD + dd] = Min;
        float2 ab = seg[(size_t)s * DPAD + dd];
        Min = fmaf(ab.x, Min, ab.y);
    }
}

// ---- pass 3: sign-pure parallelogram tiles, 24.4 KB LDS (6 blocks/CU), 128 thr.
// NEG blocks (o<=0): LDS view [64 rows][128 cols = k mod 128].
// POS blocks (o>=1): LDS view [191 rows][64 cols = k mod 64].
__global__ __launch_bounds__(128) void k_pass3t(
        const float4* __restrict__ G4, const float4* __restrict__ H4,
        const float* __restrict__ sA, const float* __restrict__ sB,
        const float* __restrict__ carr, unsigned short* __restrict__ V) {
    __shared__ unsigned short vals[191 * 64];   // 24,448 B (NEG uses first 16 KB)

    int dg = blockIdx.x;   // 0..63
    int sg = blockIdx.y;   // 0..63
    int dd0 = dg * DGRP;
    int t0 = sg * TSEG;
    int o0 = dd0 - (NN - 1);
    int o_hi = o0 + DGRP - 1;

    int minabs = (o0 >= 0) ? o0 : ((o_hi < 0) ? -o_hi : 0);
    if (t0 >= NN - minabs) return;

    int tid = threadIdx.x;   // 0..127, one diagonal each
    int dd = dd0 + tid;
    int o = dd - (NN - 1);
    float M = carr[(size_t)sg * DPAD + dd];

    if (o_hi <= 0) {
        // ---- NEG: i = t0+tl (wave-uniform), k = t0+tl-o (per-lane, coalesced) ----
        int k0 = t0 - o;
#pragma unroll 4
        for (int tl = 0; tl < TSEG; ++tl) {
            int i = t0 + tl;                 // always < NN
            int k = k0 + tl;
            int kc = k < NN ? k : NN - 1;    // virtual lanes -> unused mod-128 slots
            float4 g = G4[i], h = H4[kc];
            float f = g.x * h.x + g.y * h.y + g.z * h.z + g.w * h.w;
            float c = 0.f;
            if (t0 + tl != 0) c = sA[i - 1] * sB[kc - 1];
            M = fmaf(c, M, f);
            vals[tl * 128 + ((k & 127) ^ ((tl & 15) << 2))] = f2bf(M);
        }
        __syncthreads();

        int row_sub = tid >> 5, csub = tid & 31;
        for (int rb = 0; rb < TSEG; rb += 4) {
            int tl = rb + row_sub;
            int i = t0 + tl;
            int swz = (tl & 15) << 2;
            int k_lo = i - o_hi;                       // >= i >= 0
            int k_hi = i - o0; if (k_hi > NN - 1) k_hi = NN - 1;
            size_t rowbase = (size_t)i * NN;
            int cb_first = k_lo >> 2, cb_last = k_hi >> 2;
            for (int cc = cb_first + csub; cc <= cb_last; cc += 32) {
                int kb = cc << 2;
                if (kb >= k_lo && kb + 3 <= k_hi) {
                    int c0 = (kb & 127) ^ swz;         // swz multiple of 4 -> contiguous
                    *(ushort4*)&V[rowbase + kb] = *(const ushort4*)&vals[tl * 128 + c0];
                } else {
#pragma unroll
                    for (int j = 0; j < 4; ++j) {
                        int k = kb + j;
                        if (k < k_lo || k > k_hi) continue;
                        V[rowbase + k] = vals[tl * 128 + ((k & 127) ^ swz)];
                    }
                }
            }
        }
    } else {
        // ---- POS: k = t0+tl (wave-uniform), i = t0+tl+o (per-lane, coalesced) ----
        int i0p = t0 + o;
#pragma unroll 4
        for (int tl = 0; tl < TSEG; ++tl) {
            int i = i0p + tl;
            int k = t0 + tl;                 // always < NN
            int ic = i < NN ? i : NN - 1;    // virtual lanes -> unused rows
            float4 g = G4[ic], h = H4[k];
            float f = g.x * h.x + g.y * h.y + g.z * h.z + g.w * h.w;
            float c = 0.f;
            if (t0 + tl != 0) c = sA[ic - 1] * sB[k - 1];
            M = fmaf(c, M, f);
            int rr = tl + tid;               // i - i_lo, 0..190
            vals[rr * 64 + ((k & 63) ^ ((rr & 15) << 2))] = f2bf(M);
        }
        __syncthreads();

        int i_lo = t0 + o0;
        int i_hi = t0 + TSEG - 1 + o_hi; if (i_hi > NN - 1) i_hi = NN - 1;
        int nrows = i_hi - i_lo + 1;
        int row_sub = tid >> 4, csub = tid & 15;
        for (int rb = 0; rb < nrows; rb += 8) {
            int rr = rb + row_sub;
            int i = i_lo + rr;
            if (i > i_hi) continue;
            int swz = (rr & 15) << 2;
            int k_lo = i - o_hi; if (k_lo < t0) k_lo = t0;
            int k_hi = i - o0;  if (k_hi > t0 + TSEG - 1) k_hi = t0 + TSEG - 1;
            size_t rowbase = (size_t)i * NN;
            int cb_first = k_lo >> 2, cb_last = k_hi >> 2;
            for (int cc = cb_first + csub; cc <= cb_last; cc += 16) {
                int kb = cc << 2;
                if (kb >= k_lo && kb + 3 <= k_hi) {
                    int c0 = (kb & 63) ^ swz;
                    *(ushort4*)&V[rowbase + kb] = *(const ushort4*)&vals[rr * 64 + c0];
                } else {
#pragma unroll
                    for (int j = 0; j < 4; ++j) {
                        int k = kb + j;
                        if (k < k_lo || k > k_hi) continue;
                        V[rowbase + k] = vals[rr * 64 + ((k & 63) ^ swz)];
                    }
                }
            }
        }
    }
}

// ---- split-K GEMM: m97 structure per block. 128x128 tile, BK=64, 4 waves of
// 64x64 (16 MFMA : 8 ds_read per kk), double-buffered 2-phase, K-half per z.
// z=0 -> C (no bias), z=1 -> partial. grid (8,32,2) = 512 blocks (2/CU).
__global__ __launch_bounds__(256) void k_gemm_sk(const unsigned short* __restrict__ A,
                                                 const unsigned short* __restrict__ Bv,
                                                 float* __restrict__ C,
                                                 float* __restrict__ part) {
    __shared__ unsigned short lA[2][128 * 64];   // 2 x 16 KB
    __shared__ unsigned short lB[2][128 * 64];   // 2 x 16 KB

    // bijective XCD swizzle over 512 blocks (512 % 8 == 0)
    int flat = (blockIdx.z * 32 + blockIdx.y) * 8 + blockIdx.x;
    int swz = (flat & 7) * 64 + (flat >> 3);
    int bz = swz & 1;
    int bm = (swz >> 1) & 7;
    int bn = swz >> 4;          // 16 consecutive swz share bn -> B-panel L2 reuse

    int tid = threadIdx.x;
    int lane = tid & 63;
    int wid = tid >> 6;
    int wm = wid >> 1, wn = wid & 1;

    int kbase = bz * (NN / 2);

    const unsigned short* aptr[4];
    const unsigned short* bptr[4];
#pragma unroll
    for (int c = 0; c < 4; ++c) {
        int u = c * 256 + tid;
        aptr[c] = A + ((size_t)(bm * 128 + (u >> 3)) * NN) + kbase + (u & 7) * 8;
        bptr[c] = Bv + ((size_t)(bn * 128 + (u >> 3)) * NN) + kbase + (u & 7) * 8;
    }

    f32x4 acc[4][4];
#pragma unroll
    for (int i = 0; i < 4; ++i)
#pragma unroll
        for (int j = 0; j < 4; ++j) acc[i][j] = (f32x4){0.f, 0.f, 0.f, 0.f};

#define STAGE_SK(buf)                                                                \
    do {                                                                             \
        _Pragma("unroll") for (int c = 0; c < 4; ++c) {                              \
            __builtin_amdgcn_global_load_lds(                                        \
                (const __attribute__((address_space(1))) uint32_t*)(aptr[c]),        \
                (__attribute__((address_space(3))) uint32_t*)(&lA[buf][(c * 256 + tid) * 8]), \
                16, 0, 0);                                                           \
            aptr[c] += 64;                                                           \
            __builtin_amdgcn_global_load_lds(                                        \
                (const __attribute__((address_space(1))) uint32_t*)(bptr[c]),        \
                (__attribute__((address_space(3))) uint32_t*)(&lB[buf][(c * 256 + tid) * 8]), \
                16, 0, 0);                                                           \
            bptr[c] += 64;                                                           \
        }                                                                            \
    } while (0)

#define COMPUTE_SK(buf)                                                              \
    do {                                                                             \
        _Pragma("unroll") for (int kk = 0; kk < 2; ++kk) {                           \
            bf16x8 af[4], bfr[4];                                                    \
            _Pragma("unroll") for (int mf = 0; mf < 4; ++mf)                         \
                af[mf] = *(const bf16x8*)&lA[buf][(wm * 64 + mf * 16 + (lane & 15)) * 64 + kk * 32 + (lane >> 4) * 8]; \
            _Pragma("unroll") for (int nf = 0; nf < 4; ++nf)                         \
                bfr[nf] = *(const bf16x8*)&lB[buf][(wn * 64 + nf * 16 + (lane & 15)) * 64 + kk * 32 + (lane >> 4) * 8]; \
            _Pragma("unroll") for (int mf = 0; mf < 4; ++mf)                         \
                _Pragma("unroll") for (int nf = 0; nf < 4; ++nf)                     \
                    acc[mf][nf] = __builtin_amdgcn_mfma_f32_16x16x32_bf16(af[mf], bfr[nf], acc[mf][nf], 0, 0, 0); \
        }                                                                            \
    } while (0)

    STAGE_SK(0);
    __syncthreads();
    int cur = 0;
    for (int kt = 0; kt < NN / 2 / 64 - 1; ++kt) {
        STAGE_SK(cur ^ 1);
        COMPUTE_SK(cur);
        __syncthreads();
        cur ^= 1;
    }
    COMPUTE_SK(cur);
#undef STAGE_SK
#undef COMPUTE_SK

    float* dst = bz ? part : C;
#pragma unroll
    for (int nf = 0; nf < 4; ++nf) {
        int col = bn * 128 + wn * 64 + nf * 16 + (lane & 15);
#pragma unroll
        for (int mf = 0; mf < 4; ++mf) {
            f32x4 v = acc[mf][nf];
            int row0 = bm * 128 + wm * 64 + mf * 16 + (lane >> 4) * 4;
#pragma unroll
            for (int r = 0; r < 4; ++r)
                dst[(size_t)(row0 + r) * NN + col] = v[r];
        }
    }
}

// ---- reduce: out = out(partial0) + partial1 + bias ----
__global__ void k_reduce(float4* __restrict__ C, const float4* __restrict__ part,
                         const float4* __restrict__ bias4) {
    int idx = blockIdx.x * 256 + threadIdx.x;   // BATCH*NN/4 exactly
    float4 p = C[idx];
    float4 q = part[idx];
    float4 b = bias4[idx & (NN / 4 - 1)];
    C[idx] = make_float4(p.x + q.x + b.x, p.y + q.y + b.y,
                         p.z + q.z + b.z, p.w + q.w + b.w);
}

// ---- fallback GEMM (R4 path): BM=64 x BN=128, used only if ws too small ----
__global__ __launch_bounds__(256) void k_gemm(const unsigned short* __restrict__ A,
                                              const unsigned short* __restrict__ Bv,
                                              const float* __restrict__ bias,
                                              float* __restrict__ C) {
    __shared__ unsigned short lA[2][64 * 64];
    __shared__ unsigned short lB[2][128 * 64];

    int flat = blockIdx.y * 16 + blockIdx.x;
    int wg = (flat & 7) * 64 + (flat >> 3);
    int bm = wg & 15;
    int bn = wg >> 4;

    int tid = threadIdx.x;
    int lane = tid & 63;
    int wid = tid >> 6;
    int wm = wid >> 1, wn = wid & 1;

    const unsigned short* aptr[2];
    const unsigned short* bptr[4];
#pragma unroll
    for (int c = 0; c < 2; ++c) {
        int u = c * 256 + tid;
        aptr[c] = A + ((size_t)(bm * 64 + (u >> 3)) * NN) + (u & 7) * 8;
    }
#pragma unroll
    for (int c = 0; c < 4; ++c) {
        int u = c * 256 + tid;
        bptr[c] = Bv + ((size_t)(bn * 128 + (u >> 3)) * NN) + (u & 7) * 8;
    }

    f32x4 acc[2][4];
#pragma unroll
    for (int i = 0; i < 2; ++i)
#pragma unroll
        for (int j = 0; j < 4; ++j) acc[i][j] = (f32x4){0.f, 0.f, 0.f, 0.f};

#define STAGE(buf)                                                                   \
    do {                                                                             \
        _Pragma("unroll") for (int c = 0; c < 2; ++c) {                              \
            __builtin_amdgcn_global_load_lds(                                        \
                (const __attribute__((address_space(1))) uint32_t*)(aptr[c]),        \
                (__attribute__((address_space(3))) uint32_t*)(&lA[buf][(c * 256 + tid) * 8]), \
                16, 0, 0);                                                           \
            aptr[c] += 64;                                                           \
        }                                                                            \
        _Pragma("unroll") for (int c = 0; c < 4; ++c) {                              \
            __builtin_amdgcn_global_load_lds(                                        \
                (const __attribute__((address_space(1))) uint32_t*)(bptr[c]),        \
                (__attribute__((address_space(3))) uint32_t*)(&lB[buf][(c * 256 + tid) * 8]), \
                16, 0, 0);                                                           \
            bptr[c] += 64;                                                           \
        }                                                                            \
    } while (0)

#define COMPUTE(buf)                                                                 \
    do {                                                                             \
        _Pragma("unroll") for (int kk = 0; kk < 2; ++kk) {                           \
            bf16x8 af[2], bfr[4];                                                    \
            _Pragma("unroll") for (int mf = 0; mf < 2; ++mf)                         \
                af[mf] = *(const bf16x8*)&lA[buf][(wm * 32 + mf * 16 + (lane & 15)) * 64 + kk * 32 + (lane >> 4) * 8]; \
            _Pragma("unroll") for (int nf = 0; nf < 4; ++nf)                         \
                bfr[nf] = *(const bf16x8*)&lB[buf][(wn * 64 + nf * 16 + (lane & 15)) * 64 + kk * 32 + (lane >> 4) * 8]; \
            _Pragma("unroll") for (int mf = 0; mf < 2; ++mf)                         \
                _Pragma("unroll") for (int nf = 0; nf < 4; ++nf)                     \
                    acc[mf][nf] = __builtin_amdgcn_mfma_f32_16x16x32_bf16(af[mf], bfr[nf], acc[mf][nf], 0, 0, 0); \
        }                                                                            \
    } while (0)

    STAGE(0);
    __syncthreads();
    int cur = 0;
    for (int kt = 0; kt < NN / 64 - 1; ++kt) {
        STAGE(cur ^ 1);
        COMPUTE(cur);
        __syncthreads();
        cur ^= 1;
    }
    COMPUTE(cur);
#undef STAGE
#undef COMPUTE

#pragma unroll
    for (int nf = 0; nf < 4; ++nf) {
        int col = bn * 128 + wn * 64 + nf * 16 + (lane & 15);
        float bv = bias[col];
#pragma unroll
        for (int mf = 0; mf < 2; ++mf) {
            f32x4 v = acc[mf][nf];
            int row0 = bm * 64 + wm * 32 + mf * 16 + (lane >> 4) * 4;
#pragma unroll
            for (int r = 0; r < 4; ++r)
                C[(size_t)(row0 + r) * NN + col] = v[r] + bv;
        }
    }
}

extern "C" void kernel_launch(void* const* d_in, const int* in_sizes, int n_in,
                              void* d_out, int out_size, void* d_ws, size_t ws_size,
                              hipStream_t stream) {
    (void)in_sizes; (void)n_in; (void)out_size;
    const float* x  = (const float*)d_in[0];
    const float* sA = (const float*)d_in[1];
    const float* sB = (const float*)d_in[2];
    const float* G  = (const float*)d_in[3];
    const float* H  = (const float*)d_in[4];
    const float* bias = (const float*)d_in[5];
    float* out = (float*)d_out;

    char* ws = (char*)d_ws;
    unsigned short* V  = (unsigned short*)ws;               // 33,554,432 B
    float2* seg = (float2*)ws;                              // 4 MB, aliased on V (dead before pass3)
    unsigned short* xb = (unsigned short*)(ws + 33554432);  // 8,388,608 B
    float4* G4 = (float4*)(ws + 41943040);                  // 65,536 B
    float4* H4 = (float4*)(ws + 42008576);                  // 65,536 B
    float* carr = (float*)(ws + 42074112);                  // 2,097,152 B
    float* part = (float*)(ws + WS_PART_OFF);               // 16,777,216 B (split-K only)

    hipLaunchKernelGGL(k_prep, dim3(16), dim3(256), 0, stream, G, H, G4, H4);
    hipLaunchKernelGGL(k_convert, dim3((BATCH * NN / 4) / 256), dim3(256), 0, stream,
                       (const float4*)x, (ushort4*)xb);
    hipLaunchKernelGGL(k_pass1, dim3((NSEG * DPAD) / 256), dim3(256), 0, stream,
                       G4, H4, sA, sB, seg);
    hipLaunchKernelGGL(k_pass2, dim3(DPAD / 256), dim3(256), 0, stream, seg, carr);
    hipLaunchKernelGGL(k_pass3t, dim3(DPAD / DGRP, NN / TSEG), dim3(128), 0, stream,
                       G4, H4, sA, sB, carr, V);

    if (ws_size >= WS_SPLITK_NEED) {
        hipLaunchKernelGGL(k_gemm_sk, dim3(8, 32, 2), dim3(256), 0, stream,
                           xb, V, out, part);
        hipLaunchKernelGGL(k_reduce, dim3((BATCH * NN / 4) / 256), dim3(256), 0, stream,
                           (float4*)out, (const float4*)part, (const float4*)bias);
    } else {
        hipLaunchKernelGGL(k_gemm, dim3(BATCH / 64, NN / 128), dim3(256), 0, stream,
                           xb, V, bias, out);
    }
}